// Round 7
// baseline (97.893 us; speedup 1.0000x reference)
//
#include <hip/hip_runtime.h>

#define NB 16
#define BATCH 8
#define PLANE (512*512)           // 262144 px per channel plane
#define FBINS 512                 // fine histogram resolution
#define CHUNKS 128
#define CTHREADS 512              // count kernel: 8 waves/block
#define PX_PER_BLOCK (PLANE / CHUNKS)          // 2048 = CTHREADS*4
#define SLICES 8
#define FPB (FBINS / SLICES)                   // 64 fine bins per combine block
#define NPAIR 24                               // 3 h2-pairs * 8 batches
#define NHIST (48 * NB)                        // 768 hist floats

#if __has_builtin(__builtin_amdgcn_exp2f)
__device__ __forceinline__ float exp2_fast(float x) { return __builtin_amdgcn_exp2f(x); }
#else
__device__ __forceinline__ float exp2_fast(float x) { return __expf(x * 0.69314718056f); }
#endif

// weight = exp(-128*(x - i/15)^2) = exp2( -(128*log2(e)/225) * (15x - i)^2 )
#define NEG_C2 (-0.8207331788f)

__device__ __forceinline__ int qbin(float x) {
    int f = (int)(x * (float)FBINS);
    return f > (FBINS - 1) ? (FBINS - 1) : f;
}

// ---------------------------------------------------------------------------
// 1) masked fine histogram. LDS: 3 arrays of FBINS u32, each word packs two
//    channels (lo16 = ch 2k, hi16 = ch 2k+1). Max count/half = 2048 -> no carry.
//    512 threads = 8 waves/block, 4 blocks/CU -> 32 waves/CU.
//    Block (0,0) additionally zeroes hist[768] + counter for the next kernel
//    (visible at dispatch boundary). Channel order h: p0,p1,p2,t0,t1,t2.
// ---------------------------------------------------------------------------
__global__ __launch_bounds__(CTHREADS, 8)
void count_kernel(const float* __restrict__ pred,
                  const float* __restrict__ tgt,
                  unsigned int* __restrict__ partial, /* [3][B][CHUNKS][FBINS] */
                  float* __restrict__ hist,           /* [48][NB] + counter    */
                  unsigned int* __restrict__ counter)
{
    const int chunk = blockIdx.x;
    const int b     = blockIdx.y;
    const int tid   = threadIdx.x;

    if (chunk == 0 && b == 0) {
        for (int e = tid; e < NHIST; e += CTHREADS) hist[e] = 0.0f;
        if (tid == 0) *counter = 0u;
    }

    __shared__ unsigned int cnt[3 * FBINS];   // 6 KB
    #pragma unroll
    for (int k = 0; k < 3 * FBINS / CTHREADS; ++k)
        cnt[tid + k * CTHREADS] = 0u;
    __syncthreads();

    const float* pb = pred + (size_t)b * 3 * PLANE;
    const float* tb = tgt  + (size_t)b * 3 * PLANE;
    const int p = chunk * PX_PER_BLOCK + tid * 4;

    const float4 P0 = *(const float4*)(pb + p);
    const float4 P1 = *(const float4*)(pb + PLANE + p);
    const float4 P2 = *(const float4*)(pb + 2 * PLANE + p);
    const float4 T0 = *(const float4*)(tb + p);
    const float4 T1 = *(const float4*)(tb + PLANE + p);
    const float4 T2 = *(const float4*)(tb + 2 * PLANE + p);

    const float p0a[4] = {P0.x, P0.y, P0.z, P0.w};
    const float p1a[4] = {P1.x, P1.y, P1.z, P1.w};
    const float p2a[4] = {P2.x, P2.y, P2.z, P2.w};
    const float t0a[4] = {T0.x, T0.y, T0.z, T0.w};
    const float t1a[4] = {T1.x, T1.y, T1.z, T1.w};
    const float t2a[4] = {T2.x, T2.y, T2.z, T2.w};

    #pragma unroll
    for (int j = 0; j < 4; ++j) {
        const bool m = (t0a[j] + t1a[j] + t2a[j]) * (1.0f / 3.0f) > 0.4f;
        if (m) {
            atomicAdd(&cnt[           qbin(p0a[j])], 1u);       // h=0 lo
            atomicAdd(&cnt[           qbin(p1a[j])], 65536u);   // h=1 hi
            atomicAdd(&cnt[FBINS    + qbin(p2a[j])], 1u);       // h=2 lo
            atomicAdd(&cnt[FBINS    + qbin(t0a[j])], 65536u);   // h=3 hi
            atomicAdd(&cnt[2*FBINS  + qbin(t1a[j])], 1u);       // h=4 lo
            atomicAdd(&cnt[2*FBINS  + qbin(t2a[j])], 65536u);   // h=5 hi
        }
    }
    __syncthreads();

    // flush 1536 words -> partial[h2][b][chunk][f]
    #pragma unroll
    for (int k = 0; k < 3 * FBINS / CTHREADS; ++k) {
        const int w  = tid + k * CTHREADS;
        const int h2 = w >> 9;
        const int f  = w & (FBINS - 1);
        partial[(((size_t)h2 * BATCH + b) * CHUNKS + chunk) * FBINS + f] = cnt[w];
    }
}

// ---------------------------------------------------------------------------
// 2) fused: reduce partials over chunks (both packed channels per word) +
//    Gaussian conv -> global atomic hist; LAST block computes the loss.
//    grid (SLICES, NPAIR), 256 threads.
// ---------------------------------------------------------------------------
__global__ __launch_bounds__(256)
void combine_kernel(const unsigned int* __restrict__ partial,
                    float* __restrict__ hist,
                    unsigned int* __restrict__ counter,
                    float* __restrict__ out)
{
    const int slice = blockIdx.x;
    const int pr    = blockIdx.y;          // h2*BATCH + b
    const int h2    = pr / BATCH;
    const int b     = pr % BATCH;
    const int tid   = threadIdx.x;

    const int f_loc = tid & (FPB - 1);
    const int q     = tid >> 6;            // 0..3, chunk quarter
    const int f     = slice * FPB + f_loc;

    const unsigned int* base =
        partial + (((size_t)h2 * BATCH + b) * CHUNKS + q * 32) * FBINS + f;
    unsigned int slo = 0u, shi = 0u;
    #pragma unroll 8
    for (int c = 0; c < 32; ++c) {
        const unsigned int w = base[(size_t)c * FBINS];
        slo += w & 0xFFFFu;
        shi += w >> 16;
    }

    __shared__ unsigned int rlo[4][FPB];
    __shared__ unsigned int rhi[4][FPB];
    rlo[q][f_loc] = slo;
    rhi[q][f_loc] = shi;
    __syncthreads();

    if (tid < FPB) {   // wave 0 only
        const float clo = (float)(rlo[0][tid] + rlo[1][tid] + rlo[2][tid] + rlo[3][tid]);
        const float chi = (float)(rhi[0][tid] + rhi[1][tid] + rhi[2][tid] + rhi[3][tid]);
        const float y   = ((float)(slice * FPB + tid) + 0.5f) * (15.0f / (float)FBINS);

        float alo[NB], ahi[NB];
        #pragma unroll
        for (int i = 0; i < NB; ++i) {
            const float u = y - (float)i;
            const float w = exp2_fast(u * u * NEG_C2);
            alo[i] = clo * w;
            ahi[i] = chi * w;
        }
        #pragma unroll
        for (int off = 32; off > 0; off >>= 1) {
            #pragma unroll
            for (int i = 0; i < NB; ++i) {
                alo[i] += __shfl_down(alo[i], off, 64);
                ahi[i] += __shfl_down(ahi[i], off, 64);
            }
        }
        if (tid == 0) {
            const int hb_lo = (2 * h2    ) * BATCH + b;
            const int hb_hi = (2 * h2 + 1) * BATCH + b;
            #pragma unroll
            for (int i = 0; i < NB; ++i) {
                atomicAdd(&hist[hb_lo * NB + i], alo[i]);
                atomicAdd(&hist[hb_hi * NB + i], ahi[i]);
            }
        }
    }

    // ---- last-block-done: compute loss ----
    __threadfence();
    __shared__ unsigned int is_last;
    if (tid == 0)
        is_last = (atomicAdd(counter, 1u) == SLICES * NPAIR - 1) ? 1u : 0u;
    __syncthreads();
    if (!is_last) return;

    __threadfence();
    __shared__ float H[NHIST];             // H[(h*BATCH+b)*NB + i]
    for (int e = tid; e < NHIST; e += 256)
        H[e] = atomicAdd(&hist[e], 0.0f);  // device-coherent load
    __syncthreads();

    float val = 0.0f;
    for (int t = tid; t < 384; t += 256) { // (b, c, i) triples
        const int bb  = t / 48;
        const int rem = t % 48;
        const int c   = rem / NB;
        const int i   = rem % NB;
        const float* hp = H + ((c    ) * BATCH + bb) * NB;  // pred ch c
        const float* ht = H + ((c + 3) * BATCH + bb) * NB;  // target ch c
        float sp = 0.0f, st = 0.0f;
        #pragma unroll
        for (int k = 0; k < NB; ++k) { sp += hp[k]; st += ht[k]; }
        val += fabsf(hp[i] / (sp + 1e-7f) - ht[i] / (st + 1e-7f));
    }

    #pragma unroll
    for (int off = 32; off > 0; off >>= 1)
        val += __shfl_down(val, off, 64);

    __shared__ float r[4];
    const int lane = tid & 63, wv = tid >> 6;
    if (lane == 0) r[wv] = val;
    __syncthreads();
    if (tid == 0)
        out[0] = (r[0] + r[1] + r[2] + r[3]) * (1.0f / 384.0f);
}

extern "C" void kernel_launch(void* const* d_in, const int* in_sizes, int n_in,
                              void* d_out, int out_size, void* d_ws, size_t ws_size,
                              hipStream_t stream)
{
    const float* pred = (const float*)d_in[0];
    const float* tgt  = (const float*)d_in[1];

    const size_t part_bytes = (size_t)3 * BATCH * CHUNKS * FBINS * 4;  // 6.29 MB
    unsigned int* partial = (unsigned int*)d_ws;
    float*        hist    = (float*)((char*)d_ws + part_bytes);
    unsigned int* counter = (unsigned int*)((char*)d_ws + part_bytes + NHIST * 4);

    count_kernel<<<dim3(CHUNKS, BATCH), CTHREADS, 0, stream>>>(
        pred, tgt, partial, hist, counter);
    combine_kernel<<<dim3(SLICES, NPAIR), 256, 0, stream>>>(
        partial, hist, counter, (float*)d_out);
}

// Round 8
// 91.050 us; speedup vs baseline: 1.0752x; 1.0752x over previous
//
#include <hip/hip_runtime.h>

#define NB 16
#define BATCH 8
#define PLANE (512*512)           // 262144 px per channel plane
#define FBINS 512                 // fine histogram resolution
#define CHUNKS 128
#define CTHREADS 512              // count kernel: 8 waves/block
#define PX_PER_BLOCK (PLANE / CHUNKS)          // 2048 = CTHREADS*4
#define SLICES 8
#define FPB (FBINS / SLICES)                   // 64 fine bins per combine block
#define NPAIR 24                               // 3 h2-pairs * 8 batches

#if __has_builtin(__builtin_amdgcn_exp2f)
__device__ __forceinline__ float exp2_fast(float x) { return __builtin_amdgcn_exp2f(x); }
#else
__device__ __forceinline__ float exp2_fast(float x) { return __expf(x * 0.69314718056f); }
#endif

// weight = exp(-128*(x - i/15)^2) = exp2( -(128*log2(e)/225) * (15x - i)^2 )
#define NEG_C2 (-0.8207331788f)

__device__ __forceinline__ int qbin(float x) {
    int f = (int)(x * (float)FBINS);
    return f > (FBINS - 1) ? (FBINS - 1) : f;
}

// ---------------------------------------------------------------------------
// 1) masked fine histogram. LDS: 3 arrays of FBINS u32, each word packs two
//    channels (lo16 = ch 2k, hi16 = ch 2k+1). Max count/half = 2048 -> no carry.
//    512 threads = 8 waves/block, 1024 blocks -> 4 blocks/CU, 32 waves/CU.
//    Channel order h in [0,6): p0,p1,p2,t0,t1,t2.
// ---------------------------------------------------------------------------
__global__ __launch_bounds__(CTHREADS, 8)
void count_kernel(const float* __restrict__ pred,
                  const float* __restrict__ tgt,
                  unsigned int* __restrict__ partial
                  /* [3][BATCH][CHUNKS][FBINS] */)
{
    const int chunk = blockIdx.x;
    const int b     = blockIdx.y;
    const int tid   = threadIdx.x;

    __shared__ unsigned int cnt[3 * FBINS];   // 6 KB
    #pragma unroll
    for (int k = 0; k < 3 * FBINS / CTHREADS; ++k)
        cnt[tid + k * CTHREADS] = 0u;
    __syncthreads();

    const float* pb = pred + (size_t)b * 3 * PLANE;
    const float* tb = tgt  + (size_t)b * 3 * PLANE;
    const int p = chunk * PX_PER_BLOCK + tid * 4;

    const float4 P0 = *(const float4*)(pb + p);
    const float4 P1 = *(const float4*)(pb + PLANE + p);
    const float4 P2 = *(const float4*)(pb + 2 * PLANE + p);
    const float4 T0 = *(const float4*)(tb + p);
    const float4 T1 = *(const float4*)(tb + PLANE + p);
    const float4 T2 = *(const float4*)(tb + 2 * PLANE + p);

    const float p0a[4] = {P0.x, P0.y, P0.z, P0.w};
    const float p1a[4] = {P1.x, P1.y, P1.z, P1.w};
    const float p2a[4] = {P2.x, P2.y, P2.z, P2.w};
    const float t0a[4] = {T0.x, T0.y, T0.z, T0.w};
    const float t1a[4] = {T1.x, T1.y, T1.z, T1.w};
    const float t2a[4] = {T2.x, T2.y, T2.z, T2.w};

    #pragma unroll
    for (int j = 0; j < 4; ++j) {
        const bool m = (t0a[j] + t1a[j] + t2a[j]) * (1.0f / 3.0f) > 0.4f;
        if (m) {
            atomicAdd(&cnt[           qbin(p0a[j])], 1u);       // h=0 lo
            atomicAdd(&cnt[           qbin(p1a[j])], 65536u);   // h=1 hi
            atomicAdd(&cnt[FBINS    + qbin(p2a[j])], 1u);       // h=2 lo
            atomicAdd(&cnt[FBINS    + qbin(t0a[j])], 65536u);   // h=3 hi
            atomicAdd(&cnt[2*FBINS  + qbin(t1a[j])], 1u);       // h=4 lo
            atomicAdd(&cnt[2*FBINS  + qbin(t2a[j])], 65536u);   // h=5 hi
        }
    }
    __syncthreads();

    // flush 1536 words -> partial[h2][b][chunk][f]
    #pragma unroll
    for (int k = 0; k < 3 * FBINS / CTHREADS; ++k) {
        const int w  = tid + k * CTHREADS;
        const int h2 = w >> 9;
        const int f  = w & (FBINS - 1);
        partial[(((size_t)h2 * BATCH + b) * CHUNKS + chunk) * FBINS + f] = cnt[w];
    }
}

// ---------------------------------------------------------------------------
// 2) reduce partials over chunks (BOTH packed channels per word) + Gaussian
//    conv -> out2[slice][hb][NB].  grid (SLICES, NPAIR), 256 threads.
//    Thread t: f_loc = t&63, quarter q = t>>6 sums 32 chunks. Deterministic,
//    no atomics, no fences.
// ---------------------------------------------------------------------------
__global__ __launch_bounds__(256)
void combine_kernel(const unsigned int* __restrict__ partial,
                    float* __restrict__ out2 /* [SLICES][48][NB] */)
{
    const int slice = blockIdx.x;
    const int pr    = blockIdx.y;          // h2*BATCH + b
    const int h2    = pr / BATCH;
    const int b     = pr % BATCH;
    const int tid   = threadIdx.x;

    const int f_loc = tid & (FPB - 1);
    const int q     = tid >> 6;            // 0..3, chunk quarter
    const int f     = slice * FPB + f_loc;

    const unsigned int* base =
        partial + (((size_t)h2 * BATCH + b) * CHUNKS + q * 32) * FBINS + f;
    unsigned int slo = 0u, shi = 0u;
    #pragma unroll 8
    for (int c = 0; c < 32; ++c) {
        const unsigned int w = base[(size_t)c * FBINS];
        slo += w & 0xFFFFu;
        shi += w >> 16;
    }

    __shared__ unsigned int rlo[4][FPB];
    __shared__ unsigned int rhi[4][FPB];
    rlo[q][f_loc] = slo;
    rhi[q][f_loc] = shi;
    __syncthreads();

    if (tid < FPB) {   // wave 0 only
        const float clo = (float)(rlo[0][tid] + rlo[1][tid] + rlo[2][tid] + rlo[3][tid]);
        const float chi = (float)(rhi[0][tid] + rhi[1][tid] + rhi[2][tid] + rhi[3][tid]);
        const float y   = ((float)(slice * FPB + tid) + 0.5f) * (15.0f / (float)FBINS);

        float alo[NB], ahi[NB];
        #pragma unroll
        for (int i = 0; i < NB; ++i) {
            const float u = y - (float)i;
            const float w = exp2_fast(u * u * NEG_C2);
            alo[i] = clo * w;
            ahi[i] = chi * w;
        }
        #pragma unroll
        for (int off = 32; off > 0; off >>= 1) {
            #pragma unroll
            for (int i = 0; i < NB; ++i) {
                alo[i] += __shfl_down(alo[i], off, 64);
                ahi[i] += __shfl_down(ahi[i], off, 64);
            }
        }
        if (tid == 0) {
            const int hb_lo = (2 * h2    ) * BATCH + b;
            const int hb_hi = (2 * h2 + 1) * BATCH + b;
            float* olo = out2 + ((size_t)slice * 48 + hb_lo) * NB;
            float* ohi = out2 + ((size_t)slice * 48 + hb_hi) * NB;
            #pragma unroll
            for (int i = 0; i < NB; ++i) { olo[i] = alo[i]; ohi[i] = ahi[i]; }
        }
    }
}

// ---------------------------------------------------------------------------
// 3) sum slices, normalize, L1, mean
// ---------------------------------------------------------------------------
__global__ void finalize_kernel(const float* __restrict__ out2,
                                float* __restrict__ out)
{
    const int t = threadIdx.x;      // 384 threads
    __shared__ float H[48 * NB];    // [h*BATCH+b][i]

    for (int e = t; e < 48 * NB; e += 384) {
        float v = 0.0f;
        #pragma unroll
        for (int s = 0; s < SLICES; ++s)
            v += out2[(size_t)s * 48 * NB + e];
        H[e] = v;
    }
    __syncthreads();

    const int b   = t / 48;
    const int rem = t % 48;
    const int c   = rem / NB;
    const int i   = rem % NB;

    const float* hp = H + ((c    ) * BATCH + b) * NB;  // pred
    const float* ht = H + ((c + 3) * BATCH + b) * NB;  // target
    float sp = 0.0f, st = 0.0f;
    #pragma unroll
    for (int k = 0; k < NB; ++k) { sp += hp[k]; st += ht[k]; }

    float val = fabsf(hp[i] / (sp + 1e-7f) - ht[i] / (st + 1e-7f));

    #pragma unroll
    for (int off = 32; off > 0; off >>= 1)
        val += __shfl_down(val, off, 64);

    __shared__ float r[6];
    const int lane = t & 63, wv = t >> 6;
    if (lane == 0) r[wv] = val;
    __syncthreads();
    if (t == 0)
        out[0] = (r[0] + r[1] + r[2] + r[3] + r[4] + r[5]) * (1.0f / 384.0f);
}

extern "C" void kernel_launch(void* const* d_in, const int* in_sizes, int n_in,
                              void* d_out, int out_size, void* d_ws, size_t ws_size,
                              hipStream_t stream)
{
    const float* pred = (const float*)d_in[0];
    const float* tgt  = (const float*)d_in[1];

    unsigned int* partial = (unsigned int*)d_ws;  // 3*8*128*512*4 = 6.29 MB
    float* out2 = (float*)((char*)d_ws + (size_t)3 * BATCH * CHUNKS * FBINS * 4);

    count_kernel<<<dim3(CHUNKS, BATCH), CTHREADS, 0, stream>>>(pred, tgt, partial);
    combine_kernel<<<dim3(SLICES, NPAIR), 256, 0, stream>>>(partial, out2);
    finalize_kernel<<<1, 384, 0, stream>>>(out2, (float*)d_out);
}